// Round 1
// 11661.716 us; speedup vs baseline: 1.9914x; 1.9914x over previous
//
#include <hip/hip_runtime.h>
#include <math.h>

// VarMaskedRNN: B=32, T=1024, IN=1024, H=512, L=2, D=2, fp32 in/out.
// proj: fp32 tiled GEMM (unchanged).
// rec4: batch-parallel redesign. Recurrence is independent per batch row, so
//   blocks = 2 dir x 2 batch-groups(16) x 2 hidden-slices(256) = 8 blocks.
//   Each block keeps its 256x512 W_hh slice PERSISTENT in registers as fp16
//   MFMA B-fragments (mfma_f32_16x16x32_f16), computes 16b x 256n per step,
//   and exchanges only 8 KB/step with ONE peer block (other hidden slice)
//   via relaxed agent-scope atomics + per-block flag (proven rec3 scheme).
//   Replaces the 32-block all-to-all (~262K L3 ops/step) with a pairwise
//   exchange (~16K L3 ops/step total) and VALU-dot2 with MFMA.

#define BB 32
#define TT 1024
#define HH 512
#define KK 1024

typedef _Float16 f16x8 __attribute__((ext_vector_type(8)));
typedef float f32x4 __attribute__((ext_vector_type(4)));

// ---------------------------------------------------------------------------
// proj (unchanged from previous rounds)
// ---------------------------------------------------------------------------
__global__ __launch_bounds__(256)
void proj_kernel(const float* __restrict__ src, const float* __restrict__ noise,
                 const float* __restrict__ wih, const float* __restrict__ bih,
                 float* __restrict__ dst, int src_tmajor)
{
    __shared__ float As[16][68];
    __shared__ float Bs[16][132];

    const int tid = threadIdx.x;
    const int bm = blockIdx.x & 511;
    const int bn = blockIdx.x >> 9;
    const int mbase = bm * 64;
    const int nbase = bn * 128;

    const int aRow = tid >> 2;
    const int aK   = (tid & 3) * 4;
    const int m    = mbase + aRow;
    const int t    = m >> 5;
    const int b    = m & 31;
    const size_t srcRow = (size_t)(src_tmajor ? m : (b * TT + t)) * KK;
    const float* __restrict__ nrow = noise + (size_t)b * KK;

    const int wRow = tid >> 1;
    const int wK   = (tid & 1) * 8;
    const size_t wBase = (size_t)(nbase + wRow) * KK;

    const int tm = (tid >> 4) * 4;
    const int tn = (tid & 15) * 4;

    float acc[4][8];
#pragma unroll
    for (int i = 0; i < 4; ++i)
#pragma unroll
        for (int j = 0; j < 8; ++j) acc[i][j] = 0.f;

    for (int k0 = 0; k0 < KK; k0 += 16) {
        __syncthreads();
        {
            float4 v  = *(const float4*)(src + srcRow + k0 + aK);
            float4 nz = *(const float4*)(nrow + k0 + aK);
            As[aK + 0][aRow] = v.x * nz.x;
            As[aK + 1][aRow] = v.y * nz.y;
            As[aK + 2][aRow] = v.z * nz.z;
            As[aK + 3][aRow] = v.w * nz.w;
        }
        {
            float4 v0 = *(const float4*)(wih + wBase + k0 + wK);
            float4 v1 = *(const float4*)(wih + wBase + k0 + wK + 4);
            Bs[wK + 0][wRow] = v0.x;
            Bs[wK + 1][wRow] = v0.y;
            Bs[wK + 2][wRow] = v0.z;
            Bs[wK + 3][wRow] = v0.w;
            Bs[wK + 4][wRow] = v1.x;
            Bs[wK + 5][wRow] = v1.y;
            Bs[wK + 6][wRow] = v1.z;
            Bs[wK + 7][wRow] = v1.w;
        }
        __syncthreads();
#pragma unroll
        for (int kk = 0; kk < 16; ++kk) {
            float4 a  = *(const float4*)&As[kk][tm];
            float4 bL = *(const float4*)&Bs[kk][tn];
            float4 bH = *(const float4*)&Bs[kk][tn + 64];
            float av[4] = {a.x, a.y, a.z, a.w};
            float bv[8] = {bL.x, bL.y, bL.z, bL.w, bH.x, bH.y, bH.z, bH.w};
#pragma unroll
            for (int i = 0; i < 4; ++i)
#pragma unroll
                for (int j = 0; j < 8; ++j)
                    acc[i][j] = fmaf(av[i], bv[j], acc[i][j]);
        }
    }

    float4 bL = *(const float4*)(bih + nbase + tn);
    float4 bH = *(const float4*)(bih + nbase + tn + 64);
#pragma unroll
    for (int i = 0; i < 4; ++i) {
        size_t row = (size_t)(mbase + tm + i) * HH;
        float4 o0 = {acc[i][0] + bL.x, acc[i][1] + bL.y,
                     acc[i][2] + bL.z, acc[i][3] + bL.w};
        float4 o1 = {acc[i][4] + bH.x, acc[i][5] + bH.y,
                     acc[i][6] + bH.z, acc[i][7] + bH.w};
        *(float4*)(dst + row + nbase + tn)      = o0;
        *(float4*)(dst + row + nbase + tn + 64) = o1;
    }
}

// ---------------------------------------------------------------------------
// rec4: 8 blocks x 256 threads. bx -> d = bx&1, grp = (bx>>1)&1, slice = bx>>2.
// Block owns batches [grp*16,+16) and hidden outputs [slice*256,+256).
// gsQ LDS: g = h*nh for all 512 k, 16 batches, fp16: [64 octet][16 b][2 qw].
// Exchange buffer per (c,grp,parity): 2048 qwords (16 KB); slice s owns
// qwords [s*1024,+1024). Flags: one 64B line per (c,grp,slice).
// MFMA frag convention (mirrors verified gfx950 examples):
//   A[m=batch][k]: lane l elem i -> m=l&15, k=kq*32+(l>>4)*8+i
//   B[k][n]:       lane l elem i -> n=l&15, same k map (A/B share k placement
//                  => correct under any internal K permutation)
//   D: col=l&15, row=(l>>4)*4+reg  [guide-verified]
// ---------------------------------------------------------------------------
__global__ __launch_bounds__(256, 1)
void rec4_kernel(const float* __restrict__ xinF, const float* __restrict__ xinB,
                 const float* __restrict__ whh, const float* __restrict__ bhh,
                 const float* __restrict__ nh, const float* __restrict__ maskp,
                 float* __restrict__ outBase, float* __restrict__ finals,
                 unsigned long long* __restrict__ gbase,
                 unsigned* __restrict__ fbase,
                 int layer, int out_tmajor)
{
    __shared__ __align__(16) unsigned long long gsQ[2048];   // 16 KB
    __shared__ float outs[16][272];                          // 17 KB

    const int tid   = threadIdx.x;
    const int d     = blockIdx.x & 1;
    const int grp   = (blockIdx.x >> 1) & 1;
    const int slice = (blockIdx.x >> 2) & 1;
    const int c     = layer * 2 + d;

    const int lane = tid & 63;
    const int wv   = tid >> 6;
    const int l15  = lane & 15;
    const int l4   = lane >> 4;

    const float* __restrict__ xin = d ? xinB : xinF;

    unsigned long long* exch = gbase + (size_t)((c * 2 + grp) * 2) * 2048;
    unsigned* myflag = fbase + (((c * 2 + grp) * 2 + slice) * 16);
    unsigned* pflag  = fbase + (((c * 2 + grp) * 2 + (1 - slice)) * 16);

    // ---- W_hh slice -> persistent fp16 B-fragments (wave wv owns ntiles 4wv..4wv+3)
    f16x8 Bf[4][16];
    {
        const float* wb = whh + ((size_t)c * HH + slice * 256) * HH;
#pragma unroll
        for (int j = 0; j < 4; ++j) {
            const float* wr = wb + (size_t)((wv * 4 + j) * 16 + l15) * HH + l4 * 8;
#pragma unroll
            for (int kq = 0; kq < 16; ++kq) {
                const float* p = wr + kq * 32;
                f16x8 v;
#pragma unroll
                for (int i = 0; i < 8; ++i) v[i] = (_Float16)p[i];
                Bf[j][kq] = v;
            }
        }
    }

    // ---- pass-A mapping: thread owns (pb = tid&15, n = pn0..pn0+15)
    const int pb  = tid & 15;
    const int pn0 = (tid >> 4) * 16;
    const int gb  = grp * 16 + pb;
    float nh_r[16], bias_r[16], hold[16];
    {
        const float* np = nh + ((size_t)c * BB + gb) * HH + slice * 256 + pn0;
        const float* bp = bhh + (size_t)c * HH + slice * 256 + pn0;
#pragma unroll
        for (int i = 0; i < 16; ++i) {
            nh_r[i] = np[i]; bias_r[i] = bp[i]; hold[i] = 0.f;
        }
    }

    // zero gsQ (g at step 0 is 0)
#pragma unroll
    for (int q = 0; q < 8; ++q) gsQ[q * 256 + tid] = 0ull;

    // prefetch xin (+bias folded) and mask for s=0
    float xr[16], mr;
    {
        const int t0 = d ? (TT - 1) : 0;
        const float* xp = xin + ((size_t)t0 * BB + gb) * HH + slice * 256 + pn0;
#pragma unroll
        for (int q = 0; q < 4; ++q) {
            float4 v = *(const float4*)(xp + q * 4);
            xr[q*4+0] = v.x + bias_r[q*4+0];
            xr[q*4+1] = v.y + bias_r[q*4+1];
            xr[q*4+2] = v.z + bias_r[q*4+2];
            xr[q*4+3] = v.w + bias_r[q*4+3];
        }
        mr = maskp[(size_t)gb * TT + t0];
    }
    __syncthreads();

    for (int s = 0; s < TT; ++s) {
        const int t = d ? (TT - 1 - s) : s;

        // ---- poll peer flag, then copy peer half -> LDS (deduped, coalesced)
        if (s > 0) {
            unsigned it = 0;
            while (__hip_atomic_load(pflag, __ATOMIC_RELAXED,
                                     __HIP_MEMORY_SCOPE_AGENT) < (unsigned)s) {
                __builtin_amdgcn_s_sleep(1);
                if (++it > (1u << 24)) break;   // fail visibly, never hang
            }
            const unsigned long long* src =
                exch + (size_t)(s & 1) * 2048 + (size_t)(1 - slice) * 1024;
            unsigned long long* dst = gsQ + (size_t)(1 - slice) * 1024;
#pragma unroll
            for (int q = 0; q < 4; ++q)
                dst[q * 256 + tid] = __hip_atomic_load(&src[q * 256 + tid],
                                                       __ATOMIC_RELAXED,
                                                       __HIP_MEMORY_SCOPE_AGENT);
        }
        __syncthreads();   // B0: gsQ complete (own half from prev pass-A)

        // ---- recurrent GEMM via MFMA: 16b x 64n per wave, K=512
        f32x4 acc[4];
#pragma unroll
        for (int j = 0; j < 4; ++j) acc[j] = (f32x4){0.f, 0.f, 0.f, 0.f};
#pragma unroll
        for (int kq = 0; kq < 16; ++kq) {
            f16x8 A = *(const f16x8*)&gsQ[((size_t)(kq * 4 + l4) * 16 + l15) * 2];
#pragma unroll
            for (int j = 0; j < 4; ++j)
                acc[j] = __builtin_amdgcn_mfma_f32_16x16x32_f16(A, Bf[j][kq],
                                                                acc[j], 0, 0, 0);
        }
#pragma unroll
        for (int j = 0; j < 4; ++j) {
            const int n0 = (wv * 4 + j) * 16 + l15;
#pragma unroll
            for (int r = 0; r < 4; ++r)
                outs[l4 * 4 + r][n0] = acc[j][r];
        }
        __syncthreads();   // B1: outs ready; all gsQ reads done

        // ---- pass A: tanh + mask blend + h update (register-resident state)
        float hv[16];
#pragma unroll
        for (int i = 0; i < 16; ++i) {
            float pre = outs[pb][pn0 + i] + xr[i];
            float e  = exp2f(2.885390082f * pre);                 // 2*log2(e)*x
            float th = 1.f - 2.f * __builtin_amdgcn_rcpf(e + 1.f); // tanh(x)
            float hn = hold[i] + mr * (th - hold[i]);
            hold[i] = hn;
            hv[i]   = hn;
        }
        if (s + 1 < TT) {
            union Q { _Float16 h[4]; unsigned long long q; } u[4];
#pragma unroll
            for (int q = 0; q < 4; ++q)
#pragma unroll
                for (int i = 0; i < 4; ++i)
                    u[q].h[i] = (_Float16)(hv[q * 4 + i] * nh_r[q * 4 + i]);
            const int o0 = slice * 32 + (pn0 >> 3);
            unsigned long long* gl = &gsQ[((size_t)o0 * 16 + pb) * 2];
            gl[0]  = u[0].q;  gl[1]  = u[1].q;     // own half, for next step
            gl[32] = u[2].q;  gl[33] = u[3].q;
            unsigned long long* gw = exch + (size_t)((s + 1) & 1) * 2048
                                   + ((size_t)o0 * 16 + pb) * 2;
            __hip_atomic_store(&gw[0],  u[0].q, __ATOMIC_RELAXED, __HIP_MEMORY_SCOPE_AGENT);
            __hip_atomic_store(&gw[1],  u[1].q, __ATOMIC_RELAXED, __HIP_MEMORY_SCOPE_AGENT);
            __hip_atomic_store(&gw[32], u[2].q, __ATOMIC_RELAXED, __HIP_MEMORY_SCOPE_AGENT);
            __hip_atomic_store(&gw[33], u[3].q, __ATOMIC_RELAXED, __HIP_MEMORY_SCOPE_AGENT);
        }
        __syncthreads();   // B2: vmcnt(0) drain => g stores ack'd at coherent point

        if (tid == 0 && s + 1 < TT)
            __hip_atomic_store(myflag, (unsigned)(s + 1),
                               __ATOMIC_RELAXED, __HIP_MEMORY_SCOPE_AGENT);

        // ---- output store (off the inter-block critical path)
        {
            const size_t orow = out_tmajor
                ? ((size_t)((size_t)t * BB + gb) * 1024)
                : ((size_t)((size_t)gb * TT + t) * 1024);
            float* op = outBase + orow + d * HH + slice * 256 + pn0;
#pragma unroll
            for (int q = 0; q < 4; ++q) {
                float4 v = {hv[q*4+0], hv[q*4+1], hv[q*4+2], hv[q*4+3]};
                *(float4*)(op + q * 4) = v;
            }
        }
        // ---- prefetch xin/mask for next step
        if (s + 1 < TT) {
            const int tn = d ? (TT - 2 - s) : (s + 1);
            const float* xp = xin + ((size_t)tn * BB + gb) * HH + slice * 256 + pn0;
#pragma unroll
            for (int q = 0; q < 4; ++q) {
                float4 v = *(const float4*)(xp + q * 4);
                xr[q*4+0] = v.x + bias_r[q*4+0];
                xr[q*4+1] = v.y + bias_r[q*4+1];
                xr[q*4+2] = v.z + bias_r[q*4+2];
                xr[q*4+3] = v.w + bias_r[q*4+3];
            }
            mr = maskp[(size_t)gb * TT + tn];
        }
    }

    // finals
    {
        float* fp = finals + ((size_t)c * BB + gb) * HH + slice * 256 + pn0;
#pragma unroll
        for (int q = 0; q < 4; ++q) {
            float4 v = {hold[q*4+0], hold[q*4+1], hold[q*4+2], hold[q*4+3]};
            *(float4*)(fp + q * 4) = v;
        }
    }
}

// ---------------------------------------------------------------------------
extern "C" void kernel_launch(void* const* d_in, const int* in_sizes, int n_in,
                              void* d_out, int out_size, void* d_ws, size_t ws_size,
                              hipStream_t stream)
{
    (void)in_sizes; (void)n_in; (void)out_size; (void)ws_size;

    const float* x    = (const float*)d_in[0];
    const float* mask = (const float*)d_in[1];
    const float* wih  = (const float*)d_in[2];
    const float* whh  = (const float*)d_in[3];
    const float* bih  = (const float*)d_in[4];
    const float* bhh  = (const float*)d_in[5];
    const float* nin  = (const float*)d_in[6];
    const float* nh   = (const float*)d_in[7];

    float* out    = (float*)d_out;
    float* xinF   = (float*)d_ws;                        // [T,B,512]
    float* xinB   = xinF + (size_t)TT * BB * HH;         // [T,B,512]
    unsigned long long* gbase =
        (unsigned long long*)(xinB + (size_t)TT * BB * HH);  // 16 x 16 KB
    unsigned* fbase = (unsigned*)(gbase + 16 * 2048);        // 16 x 64 B flags
    float* seq0   = out;
    float* finals = out + (size_t)BB * TT * 1024;

    // zero exchange buffers + flags (ws is poisoned before every launch)
    hipMemsetAsync(gbase, 0, 16 * 2048 * sizeof(unsigned long long) + 16 * 64,
                   stream);

    // ---- layer 0
    proj_kernel<<<2048, 256, 0, stream>>>(x, nin + 0 * (size_t)BB * KK,
                                          wih + 0 * (size_t)HH * KK,
                                          bih + 0 * HH, xinF, 0);
    proj_kernel<<<2048, 256, 0, stream>>>(x, nin + 1 * (size_t)BB * KK,
                                          wih + 1 * (size_t)HH * KK,
                                          bih + 1 * HH, xinB, 0);
    rec4_kernel<<<8, 256, 0, stream>>>(xinF, xinB, whh, bhh, nh, mask,
                                       seq0, finals, gbase, fbase, 0, 1);
    // ---- layer 1
    proj_kernel<<<2048, 256, 0, stream>>>(seq0, nin + 2 * (size_t)BB * KK,
                                          wih + 2 * (size_t)HH * KK,
                                          bih + 2 * HH, xinF, 1);
    proj_kernel<<<2048, 256, 0, stream>>>(seq0, nin + 3 * (size_t)BB * KK,
                                          wih + 3 * (size_t)HH * KK,
                                          bih + 3 * HH, xinB, 1);
    rec4_kernel<<<8, 256, 0, stream>>>(xinF, xinB, whh, bhh, nh, mask,
                                       out, finals, gbase, fbase, 1, 0);
}

// Round 2
// 11184.109 us; speedup vs baseline: 2.0764x; 1.0427x over previous
//
#include <hip/hip_runtime.h>
#include <math.h>

// VarMaskedRNN: B=32, T=1024, IN=1024, H=512, L=2, D=2, fp32 in/out.
// proj: fp32 tiled GEMM (unchanged).
// rec5: rec4's batch-parallel MFMA recurrence (8 blocks = 2 dir x 2 batch-grp
//   x 2 hidden-slice, W_hh persistent in regs as fp16 MFMA B-frags) with the
//   pairwise exchange rebuilt as SINGLE-LATENCY self-describing words:
//   each 8B word = {2 x fp16 payload (lo32) | step seq (hi32)} stored with one
//   relaxed agent-scope 64b atomic. No flag, no pre-flag vmcnt drain, no
//   detect-then-load double RT: receiver hard-spins loading its pairs until
//   seq == s (payload+seq consistent per 8B atomic). Parity double-buffer
//   kept (seeing peer g(s) proves peer consumed my g(s-1)). 2 barriers/step.

#define BB 32
#define TT 1024
#define HH 512
#define KK 1024

typedef _Float16 f16x8 __attribute__((ext_vector_type(8)));
typedef float f32x4 __attribute__((ext_vector_type(4)));

// ---------------------------------------------------------------------------
// proj (unchanged)
// ---------------------------------------------------------------------------
__global__ __launch_bounds__(256)
void proj_kernel(const float* __restrict__ src, const float* __restrict__ noise,
                 const float* __restrict__ wih, const float* __restrict__ bih,
                 float* __restrict__ dst, int src_tmajor)
{
    __shared__ float As[16][68];
    __shared__ float Bs[16][132];

    const int tid = threadIdx.x;
    const int bm = blockIdx.x & 511;
    const int bn = blockIdx.x >> 9;
    const int mbase = bm * 64;
    const int nbase = bn * 128;

    const int aRow = tid >> 2;
    const int aK   = (tid & 3) * 4;
    const int m    = mbase + aRow;
    const int t    = m >> 5;
    const int b    = m & 31;
    const size_t srcRow = (size_t)(src_tmajor ? m : (b * TT + t)) * KK;
    const float* __restrict__ nrow = noise + (size_t)b * KK;

    const int wRow = tid >> 1;
    const int wK   = (tid & 1) * 8;
    const size_t wBase = (size_t)(nbase + wRow) * KK;

    const int tm = (tid >> 4) * 4;
    const int tn = (tid & 15) * 4;

    float acc[4][8];
#pragma unroll
    for (int i = 0; i < 4; ++i)
#pragma unroll
        for (int j = 0; j < 8; ++j) acc[i][j] = 0.f;

    for (int k0 = 0; k0 < KK; k0 += 16) {
        __syncthreads();
        {
            float4 v  = *(const float4*)(src + srcRow + k0 + aK);
            float4 nz = *(const float4*)(nrow + k0 + aK);
            As[aK + 0][aRow] = v.x * nz.x;
            As[aK + 1][aRow] = v.y * nz.y;
            As[aK + 2][aRow] = v.z * nz.z;
            As[aK + 3][aRow] = v.w * nz.w;
        }
        {
            float4 v0 = *(const float4*)(wih + wBase + k0 + wK);
            float4 v1 = *(const float4*)(wih + wBase + k0 + wK + 4);
            Bs[wK + 0][wRow] = v0.x;
            Bs[wK + 1][wRow] = v0.y;
            Bs[wK + 2][wRow] = v0.z;
            Bs[wK + 3][wRow] = v0.w;
            Bs[wK + 4][wRow] = v1.x;
            Bs[wK + 5][wRow] = v1.y;
            Bs[wK + 6][wRow] = v1.z;
            Bs[wK + 7][wRow] = v1.w;
        }
        __syncthreads();
#pragma unroll
        for (int kk = 0; kk < 16; ++kk) {
            float4 a  = *(const float4*)&As[kk][tm];
            float4 bL = *(const float4*)&Bs[kk][tn];
            float4 bH = *(const float4*)&Bs[kk][tn + 64];
            float av[4] = {a.x, a.y, a.z, a.w};
            float bv[8] = {bL.x, bL.y, bL.z, bL.w, bH.x, bH.y, bH.z, bH.w};
#pragma unroll
            for (int i = 0; i < 4; ++i)
#pragma unroll
                for (int j = 0; j < 8; ++j)
                    acc[i][j] = fmaf(av[i], bv[j], acc[i][j]);
        }
    }

    float4 bL = *(const float4*)(bih + nbase + tn);
    float4 bH = *(const float4*)(bih + nbase + tn + 64);
#pragma unroll
    for (int i = 0; i < 4; ++i) {
        size_t row = (size_t)(mbase + tm + i) * HH;
        float4 o0 = {acc[i][0] + bL.x, acc[i][1] + bL.y,
                     acc[i][2] + bL.z, acc[i][3] + bL.w};
        float4 o1 = {acc[i][4] + bH.x, acc[i][5] + bH.y,
                     acc[i][6] + bH.z, acc[i][7] + bH.w};
        *(float4*)(dst + row + nbase + tn)      = o0;
        *(float4*)(dst + row + nbase + tn + 64) = o1;
    }
}

// ---------------------------------------------------------------------------
// rec5: 8 blocks x 256 threads. bx -> d = bx&1, grp = (bx>>1)&1, slice = bx>>2.
// Exchange region per (c,grp): 2 parity x 4096 pairs (8B each) = 64 KB.
//   pair layout mirrors gsQ: half = slice*2048 pairs; within half,
//   pair = qrel*2 + j where qrel = gsQ-qword index rel. to half base,
//   j = word-within-qword. word = {payload lo32 | seq hi32}.
// gsQ LDS: [64 octet][16 b][2 qw] fp16 (qword = 4 f16), as rec4.
// MFMA frag convention unchanged (verified):
//   A lane l elem i -> m=l&15, k=kq*32+(l>>4)*8+i ; B same k map, n=l&15;
//   D: col=l&15, row=(l>>4)*4+reg.
// ---------------------------------------------------------------------------
__global__ __launch_bounds__(256, 1)
void rec5_kernel(const float* __restrict__ xinF, const float* __restrict__ xinB,
                 const float* __restrict__ whh, const float* __restrict__ bhh,
                 const float* __restrict__ nh, const float* __restrict__ maskp,
                 float* __restrict__ outBase, float* __restrict__ finals,
                 unsigned long long* __restrict__ gbase,
                 int layer, int out_tmajor)
{
    __shared__ __align__(16) unsigned long long gsQ[2048];   // 16 KB
    __shared__ float outs[16][272];                          // 17 KB

    const int tid   = threadIdx.x;
    const int d     = blockIdx.x & 1;
    const int grp   = (blockIdx.x >> 1) & 1;
    const int slice = (blockIdx.x >> 2) & 1;
    const int c     = layer * 2 + d;

    const int lane = tid & 63;
    const int wv   = tid >> 6;
    const int l15  = lane & 15;
    const int l4   = lane >> 4;

    const float* __restrict__ xin = d ? xinB : xinF;

    // per (c,grp): 2 parity x 4096 pairs
    unsigned long long* exch = gbase + (size_t)(c * 2 + grp) * 8192;

    // ---- W_hh slice -> persistent fp16 B-fragments
    f16x8 Bf[4][16];
    {
        const float* wb = whh + ((size_t)c * HH + slice * 256) * HH;
#pragma unroll
        for (int j = 0; j < 4; ++j) {
            const float* wr = wb + (size_t)((wv * 4 + j) * 16 + l15) * HH + l4 * 8;
#pragma unroll
            for (int kq = 0; kq < 16; ++kq) {
                const float* p = wr + kq * 32;
                f16x8 v;
#pragma unroll
                for (int i = 0; i < 8; ++i) v[i] = (_Float16)p[i];
                Bf[j][kq] = v;
            }
        }
    }

    // ---- pass-A mapping: thread owns (pb = tid&15, n = pn0..pn0+15)
    const int pb  = tid & 15;
    const int pn0 = (tid >> 4) * 16;
    const int gb  = grp * 16 + pb;
    float nh_r[16], bias_r[16], hold[16];
    {
        const float* np = nh + ((size_t)c * BB + gb) * HH + slice * 256 + pn0;
        const float* bp = bhh + (size_t)c * HH + slice * 256 + pn0;
#pragma unroll
        for (int i = 0; i < 16; ++i) {
            nh_r[i] = np[i]; bias_r[i] = bp[i]; hold[i] = 0.f;
        }
    }

    // zero gsQ (g at step 0 is 0)
#pragma unroll
    for (int q = 0; q < 8; ++q) gsQ[q * 256 + tid] = 0ull;

    // prefetch xin (+bias folded) and mask for s=0
    float xr[16], mr;
    {
        const int t0 = d ? (TT - 1) : 0;
        const float* xp = xin + ((size_t)t0 * BB + gb) * HH + slice * 256 + pn0;
#pragma unroll
        for (int q = 0; q < 4; ++q) {
            float4 v = *(const float4*)(xp + q * 4);
            xr[q*4+0] = v.x + bias_r[q*4+0];
            xr[q*4+1] = v.y + bias_r[q*4+1];
            xr[q*4+2] = v.z + bias_r[q*4+2];
            xr[q*4+3] = v.w + bias_r[q*4+3];
        }
        mr = maskp[(size_t)gb * TT + t0];
    }

    for (int s = 0; s < TT; ++s) {
        const int t = d ? (TT - 1 - s) : s;

        // ---- recv peer half: spin-load self-describing pairs until seq==s
        if (s > 0) {
            const unsigned long long* src =
                exch + (size_t)(s & 1) * 4096 + (size_t)(1 - slice) * 2048;
            const unsigned target = (unsigned)s;
            unsigned long long v[8];
            unsigned it = 0;
            for (;;) {
                bool ok = true;
#pragma unroll
                for (int q = 0; q < 4; ++q) {
                    v[q*2+0] = __hip_atomic_load(&src[(size_t)(tid + q*256)*2 + 0],
                                                 __ATOMIC_RELAXED,
                                                 __HIP_MEMORY_SCOPE_AGENT);
                    v[q*2+1] = __hip_atomic_load(&src[(size_t)(tid + q*256)*2 + 1],
                                                 __ATOMIC_RELAXED,
                                                 __HIP_MEMORY_SCOPE_AGENT);
                }
#pragma unroll
                for (int i = 0; i < 8; ++i)
                    ok &= ((unsigned)(v[i] >> 32) == target);
                if (ok) break;
                if (++it > (1u << 18)) break;   // fail visibly, never hang
            }
            unsigned long long* dst = gsQ + (size_t)(1 - slice) * 1024;
#pragma unroll
            for (int q = 0; q < 4; ++q) {
                unsigned lo = (unsigned)v[q*2+0];
                unsigned hi = (unsigned)v[q*2+1];
                dst[tid + q*256] = ((unsigned long long)hi << 32) | lo;
            }
        }
        __syncthreads();   // B0: gsQ complete (own half from prev pass-A)

        // ---- recurrent GEMM via MFMA: 16b x 64n per wave, K=512
        f32x4 acc[4];
#pragma unroll
        for (int j = 0; j < 4; ++j) acc[j] = (f32x4){0.f, 0.f, 0.f, 0.f};
#pragma unroll
        for (int kq = 0; kq < 16; ++kq) {
            f16x8 A = *(const f16x8*)&gsQ[((size_t)(kq * 4 + l4) * 16 + l15) * 2];
#pragma unroll
            for (int j = 0; j < 4; ++j)
                acc[j] = __builtin_amdgcn_mfma_f32_16x16x32_f16(A, Bf[j][kq],
                                                                acc[j], 0, 0, 0);
        }
#pragma unroll
        for (int j = 0; j < 4; ++j) {
            const int n0 = (wv * 4 + j) * 16 + l15;
#pragma unroll
            for (int r = 0; r < 4; ++r)
                outs[l4 * 4 + r][n0] = acc[j][r];
        }
        __syncthreads();   // B1: outs ready; all gsQ reads done

        // ---- pass A: tanh + mask blend + h update; exchange stores FIRST
        float hv[16];
#pragma unroll
        for (int i = 0; i < 16; ++i) {
            float pre = outs[pb][pn0 + i] + xr[i];
            float e  = exp2f(2.885390082f * pre);                  // 2*log2(e)*x
            float th = 1.f - 2.f * __builtin_amdgcn_rcpf(e + 1.f); // tanh(x)
            float hn = hold[i] + mr * (th - hold[i]);
            hold[i] = hn;
            hv[i]   = hn;
        }
        if (s + 1 < TT) {
            union Q { _Float16 h[4]; unsigned long long q; unsigned w[2]; } u[4];
#pragma unroll
            for (int q = 0; q < 4; ++q)
#pragma unroll
                for (int i = 0; i < 4; ++i)
                    u[q].h[i] = (_Float16)(hv[q * 4 + i] * nh_r[q * 4 + i]);

            const unsigned long long seqhi =
                ((unsigned long long)(unsigned)(s + 1)) << 32;
            // pairs for own half: base pair = (pn0>>3)*64 + pb*4
            unsigned long long* gw = exch + (size_t)((s + 1) & 1) * 4096
                                   + (size_t)slice * 2048
                                   + (size_t)((pn0 >> 3) * 64 + pb * 4);
            __hip_atomic_store(&gw[0],  (unsigned long long)u[0].w[0] | seqhi,
                               __ATOMIC_RELAXED, __HIP_MEMORY_SCOPE_AGENT);
            __hip_atomic_store(&gw[1],  (unsigned long long)u[0].w[1] | seqhi,
                               __ATOMIC_RELAXED, __HIP_MEMORY_SCOPE_AGENT);
            __hip_atomic_store(&gw[2],  (unsigned long long)u[1].w[0] | seqhi,
                               __ATOMIC_RELAXED, __HIP_MEMORY_SCOPE_AGENT);
            __hip_atomic_store(&gw[3],  (unsigned long long)u[1].w[1] | seqhi,
                               __ATOMIC_RELAXED, __HIP_MEMORY_SCOPE_AGENT);
            __hip_atomic_store(&gw[64], (unsigned long long)u[2].w[0] | seqhi,
                               __ATOMIC_RELAXED, __HIP_MEMORY_SCOPE_AGENT);
            __hip_atomic_store(&gw[65], (unsigned long long)u[2].w[1] | seqhi,
                               __ATOMIC_RELAXED, __HIP_MEMORY_SCOPE_AGENT);
            __hip_atomic_store(&gw[66], (unsigned long long)u[3].w[0] | seqhi,
                               __ATOMIC_RELAXED, __HIP_MEMORY_SCOPE_AGENT);
            __hip_atomic_store(&gw[67], (unsigned long long)u[3].w[1] | seqhi,
                               __ATOMIC_RELAXED, __HIP_MEMORY_SCOPE_AGENT);

            // own half -> LDS for next step's MFMA
            unsigned long long* gl =
                &gsQ[((size_t)(slice * 32 + (pn0 >> 3)) * 16 + pb) * 2];
            gl[0]  = u[0].q;  gl[1]  = u[1].q;
            gl[32] = u[2].q;  gl[33] = u[3].q;
        }

        // ---- output store (off the peer-visibility path)
        {
            const size_t orow = out_tmajor
                ? ((size_t)((size_t)t * BB + gb) * 1024)
                : ((size_t)((size_t)gb * TT + t) * 1024);
            float* op = outBase + orow + d * HH + slice * 256 + pn0;
#pragma unroll
            for (int q = 0; q < 4; ++q) {
                float4 v = {hv[q*4+0], hv[q*4+1], hv[q*4+2], hv[q*4+3]};
                *(float4*)(op + q * 4) = v;
            }
        }
        // ---- prefetch xin/mask for next step
        if (s + 1 < TT) {
            const int tn = d ? (TT - 2 - s) : (s + 1);
            const float* xp = xin + ((size_t)tn * BB + gb) * HH + slice * 256 + pn0;
#pragma unroll
            for (int q = 0; q < 4; ++q) {
                float4 v = *(const float4*)(xp + q * 4);
                xr[q*4+0] = v.x + bias_r[q*4+0];
                xr[q*4+1] = v.y + bias_r[q*4+1];
                xr[q*4+2] = v.z + bias_r[q*4+2];
                xr[q*4+3] = v.w + bias_r[q*4+3];
            }
            mr = maskp[(size_t)gb * TT + tn];
        }
    }

    // finals
    {
        float* fp = finals + ((size_t)c * BB + gb) * HH + slice * 256 + pn0;
#pragma unroll
        for (int q = 0; q < 4; ++q) {
            float4 v = {hold[q*4+0], hold[q*4+1], hold[q*4+2], hold[q*4+3]};
            *(float4*)(fp + q * 4) = v;
        }
    }
}

// ---------------------------------------------------------------------------
extern "C" void kernel_launch(void* const* d_in, const int* in_sizes, int n_in,
                              void* d_out, int out_size, void* d_ws, size_t ws_size,
                              hipStream_t stream)
{
    (void)in_sizes; (void)n_in; (void)out_size; (void)ws_size;

    const float* x    = (const float*)d_in[0];
    const float* mask = (const float*)d_in[1];
    const float* wih  = (const float*)d_in[2];
    const float* whh  = (const float*)d_in[3];
    const float* bih  = (const float*)d_in[4];
    const float* bhh  = (const float*)d_in[5];
    const float* nin  = (const float*)d_in[6];
    const float* nh   = (const float*)d_in[7];

    float* out    = (float*)d_out;
    float* xinF   = (float*)d_ws;                        // [T,B,512]
    float* xinB   = xinF + (size_t)TT * BB * HH;         // [T,B,512]
    unsigned long long* gbase =
        (unsigned long long*)(xinB + (size_t)TT * BB * HH);  // 8 x 64 KB
    float* seq0   = out;
    float* finals = out + (size_t)BB * TT * 1024;

    // zero exchange buffers: stale/poisoned seq words must not equal any
    // target step (targets are >=1; zero is safe)
    hipMemsetAsync(gbase, 0, 8 * 8192 * sizeof(unsigned long long), stream);

    // ---- layer 0
    proj_kernel<<<2048, 256, 0, stream>>>(x, nin + 0 * (size_t)BB * KK,
                                          wih + 0 * (size_t)HH * KK,
                                          bih + 0 * HH, xinF, 0);
    proj_kernel<<<2048, 256, 0, stream>>>(x, nin + 1 * (size_t)BB * KK,
                                          wih + 1 * (size_t)HH * KK,
                                          bih + 1 * HH, xinB, 0);
    rec5_kernel<<<8, 256, 0, stream>>>(xinF, xinB, whh, bhh, nh, mask,
                                       seq0, finals, gbase, 0, 1);
    // ---- layer 1
    proj_kernel<<<2048, 256, 0, stream>>>(seq0, nin + 2 * (size_t)BB * KK,
                                          wih + 2 * (size_t)HH * KK,
                                          bih + 2 * HH, xinF, 1);
    proj_kernel<<<2048, 256, 0, stream>>>(seq0, nin + 3 * (size_t)BB * KK,
                                          wih + 3 * (size_t)HH * KK,
                                          bih + 3 * HH, xinB, 1);
    rec5_kernel<<<8, 256, 0, stream>>>(xinF, xinB, whh, bhh, nh, mask,
                                       out, finals, gbase, 1, 0);
}